// Round 1
// baseline (382.809 us; speedup 1.0000x reference)
//
#include <hip/hip_runtime.h>
#include <math.h>

static constexpr int B = 32, C = 256, HH = 64, WW = 64, HW = 4096, CS = 16;
static constexpr int BHW = B * HW;            // 131072
static constexpr size_t IMG = (size_t)B * CS * HW; // 2,097,152 floats per branch buffer

// ---------- workspace layout (floats) ----------
static constexpr size_t OFF_S     = 0;        // 8 ops x 512 (b*16+k) per-(b,c) sums
static constexpr size_t OFF_SQ    = 4096;     // 8 ops x 512 sumsq
static constexpr size_t OFF_U     = 8192;     // u1sum[16],u1sq[16],u2sum[16],u2sq[16]
static constexpr size_t ACC_FLOATS= 8256;     // zeroed each launch
static constexpr size_t OFF_MX    = 8256;
static constexpr size_t OFF_AV    = OFF_MX + 8192;
static constexpr size_t OFF_NUM   = OFF_AV + 8192;
static constexpr size_t OFF_SLIST = OFF_NUM + 8192;
static constexpr size_t OFF_Y     = OFF_SLIST + 256;   // B*128
static constexpr size_t OFF_ACO   = OFF_Y + 4096;      // B*16*8
static constexpr size_t OFF_BIAS  = OFF_ACO + 4096;    // B*16
static constexpr size_t OFF_INT   = OFF_BIAS + 512;    // idx[16], selmap[256] as ints
static constexpr size_t OFF_XT    = 42112;
static constexpr size_t OFF_R     = OFF_XT + IMG;      // 6 branch buffers

__device__ inline float wave_sum(float v) {
  v += __shfl_down(v, 32); v += __shfl_down(v, 16); v += __shfl_down(v, 8);
  v += __shfl_down(v, 4);  v += __shfl_down(v, 2);  v += __shfl_down(v, 1);
  return v;
}
__device__ inline float wave_max(float v) {
  v = fmaxf(v, __shfl_down(v, 32)); v = fmaxf(v, __shfl_down(v, 16));
  v = fmaxf(v, __shfl_down(v, 8));  v = fmaxf(v, __shfl_down(v, 4));
  v = fmaxf(v, __shfl_down(v, 2));  v = fmaxf(v, __shfl_down(v, 1));
  return v;
}

// ---- K1: per-(b,c) max and mean over HxW ----
__global__ __launch_bounds__(256) void k_stats(const float4* __restrict__ x,
                                               float* __restrict__ mx, float* __restrict__ av) {
  int bc = blockIdx.x;
  const float4* p = x + (size_t)bc * 1024;
  float mmax = -INFINITY, msum = 0.f;
  for (int i = threadIdx.x; i < 1024; i += 256) {
    float4 v = p[i];
    mmax = fmaxf(mmax, fmaxf(fmaxf(v.x, v.y), fmaxf(v.z, v.w)));
    msum += v.x + v.y + v.z + v.w;
  }
  __shared__ float rs[4], rm[4];
  float s = wave_sum(msum), m = wave_max(mmax);
  int w = threadIdx.x >> 6;
  if ((threadIdx.x & 63) == 0) { rs[w] = s; rm[w] = m; }
  __syncthreads();
  if (threadIdx.x == 0) {
    mx[bc] = fmaxf(fmaxf(rm[0], rm[1]), fmaxf(rm[2], rm[3]));
    av[bc] = (rs[0] + rs[1] + rs[2] + rs[3]) * (1.f / 4096.f);
  }
}

// ---- K2: SE module -> num = sigmoid(se(mx)+se(av)) ----
__global__ __launch_bounds__(128) void k_se(const float* __restrict__ mx, const float* __restrict__ av,
                                            const float* __restrict__ w1, const float* __restrict__ w2,
                                            float* __restrict__ num) {
  int b = blockIdx.x, t = threadIdx.x;
  __shared__ float zs[2][256], h[2][128];
  for (int i = t; i < 256; i += 128) { zs[0][i] = mx[b * 256 + i]; zs[1][i] = av[b * 256 + i]; }
  __syncthreads();
  {
    const float* wr = w1 + (size_t)t * 256;
    float am = 0.f, aa = 0.f;
    for (int i = 0; i < 256; i++) { float w = wr[i]; am = fmaf(w, zs[0][i], am); aa = fmaf(w, zs[1][i], aa); }
    h[0][t] = fmaxf(am, 0.f); h[1][t] = fmaxf(aa, 0.f);
  }
  __syncthreads();
  for (int c = t; c < 256; c += 128) {
    const float* wr = w2 + (size_t)c * 128;
    float sm = 0.f, sa = 0.f;
    for (int j = 0; j < 128; j++) { float w = wr[j]; sm = fmaf(w, h[0][j], sm); sa = fmaf(w, h[1][j], sa); }
    float s = sm + sa;
    num[b * 256 + c] = 1.f / (1.f + expf(-s));
  }
}

// ---- K3: slist + top-16 (lax.top_k tie-break: lowest index first) ----
__global__ __launch_bounds__(256) void k_select(const float* __restrict__ num, float* __restrict__ slist,
                                                int* __restrict__ idx, int* __restrict__ selmap) {
  __shared__ float s[256];
  int t = threadIdx.x;
  float acc = 0.f;
  for (int b = 0; b < B; b++) acc += num[b * 256 + t];
  s[t] = acc; slist[t] = acc; selmap[t] = -1;
  __syncthreads();
  if (t == 0) {
    for (int k = 0; k < 16; k++) {
      int best = 0; float bv = s[0];
      for (int c = 1; c < 256; c++) if (s[c] > bv) { bv = s[c]; best = c; }
      idx[k] = best; s[best] = -INFINITY; selmap[best] = k;
    }
  }
}

// ---- K4: xt = x[:,idx]*num ; also per-(b,k) sum (identity-branch mean) ----
__global__ __launch_bounds__(256) void k_gather(const float* __restrict__ x, const float* __restrict__ num,
                                                const int* __restrict__ idx, float* __restrict__ xt,
                                                float* __restrict__ Sdst) {
  int bk = blockIdx.x, b = bk >> 4, k = bk & 15;
  int c = idx[k];
  float sc = num[b * 256 + c];
  const float4* src = (const float4*)(x + ((size_t)b * 256 + c) * HW);
  float4* dst = (float4*)(xt + (size_t)bk * HW);
  float sum = 0.f;
  for (int i = threadIdx.x; i < 1024; i += 256) {
    float4 v = src[i];
    v.x *= sc; v.y *= sc; v.z *= sc; v.w *= sc;
    dst[i] = v; sum += v.x + v.y + v.z + v.w;
  }
  __shared__ float rs[4];
  float s = wave_sum(sum);
  if ((threadIdx.x & 63) == 0) rs[threadIdx.x >> 6] = s;
  __syncthreads();
  if (threadIdx.x == 0) Sdst[bk] = rs[0] + rs[1] + rs[2] + rs[3];
}

// ---- pools (3x3 stride1 pad1), write raw output + per-(b,c) sum/sumsq ----
template<int ISMAX>
__global__ __launch_bounds__(256) void k_pool(const float* __restrict__ xt, float* __restrict__ r,
                                              float* __restrict__ Sdst, float* __restrict__ SQdst) {
  __shared__ float tile[64 * 64];
  int bk = blockIdx.x;
  const float* src = xt + (size_t)bk * HW;
  for (int i = threadIdx.x; i < HW; i += 256) tile[i] = src[i];
  __syncthreads();
  float sum = 0.f, sq = 0.f;
  for (int i = threadIdx.x; i < HW; i += 256) {
    int y = i >> 6, x = i & 63;
    int y0 = max(y - 1, 0), y1 = min(y + 1, 63), x0 = max(x - 1, 0), x1 = min(x + 1, 63);
    float o;
    if (ISMAX) {
      o = -INFINITY;
      for (int yy = y0; yy <= y1; yy++)
        for (int xx = x0; xx <= x1; xx++) o = fmaxf(o, tile[yy * 64 + xx]);
    } else {
      float a = 0.f;
      for (int yy = y0; yy <= y1; yy++)
        for (int xx = x0; xx <= x1; xx++) a += tile[yy * 64 + xx];
      o = a / (float)((y1 - y0 + 1) * (x1 - x0 + 1));
    }
    r[(size_t)bk * HW + i] = o; sum += o; sq += o * o;
  }
  __shared__ float rs[4], rq[4];
  float s = wave_sum(sum), q = wave_sum(sq);
  if ((threadIdx.x & 63) == 0) { rs[threadIdx.x >> 6] = s; rq[threadIdx.x >> 6] = q; }
  __syncthreads();
  if (threadIdx.x == 0) {
    Sdst[bk] = rs[0] + rs[1] + rs[2] + rs[3];
    SQdst[bk] = rq[0] + rq[1] + rq[2] + rq[3];
  }
}

// ---- depthwise conv, MODE0: relu(in); MODE1: relu((in-m)*rs) with channel stats from ustats ----
template<int K, int DIL, int MODE>
__global__ __launch_bounds__(256) void k_dw(const float* __restrict__ in, const float* __restrict__ w,
                                            float* __restrict__ out, const float* __restrict__ ustats) {
  constexpr int P = (K / 2) * DIL;
  constexpr int TW = 64 + 2 * P;
  __shared__ float tile[TW * TW];
  __shared__ float sm_, srs_;
  int bk = blockIdx.x, k = bk & 15;
  if (MODE == 1) {
    if (threadIdx.x == 0) {
      float mu = ustats[k] * (1.f / (float)BHW);
      float var = ustats[16 + k] * (1.f / (float)BHW) - mu * mu;
      sm_ = mu; srs_ = rsqrtf(var + 1e-5f);
    }
    __syncthreads();
  }
  float m = (MODE == 1) ? sm_ : 0.f, rsc = (MODE == 1) ? srs_ : 1.f;
  float wr[K * K];
#pragma unroll
  for (int i = 0; i < K * K; i++) wr[i] = w[k * K * K + i];
  const float* src = in + (size_t)bk * HW;
  for (int i = threadIdx.x; i < TW * TW; i += 256) {
    int ty = i / TW, tx = i - ty * TW;
    int y = ty - P, x = tx - P;
    float v = 0.f;
    if (y >= 0 && y < 64 && x >= 0 && x < 64) {
      v = src[y * 64 + x];
      if (MODE == 1) v = (v - m) * rsc;
      v = fmaxf(v, 0.f);
    }
    tile[i] = v;
  }
  __syncthreads();
  float* dst = out + (size_t)bk * HW;
  for (int i = threadIdx.x; i < HW; i += 256) {
    int y = i >> 6, x = i & 63;
    float acc = 0.f;
#pragma unroll
    for (int a = 0; a < K; a++)
#pragma unroll
      for (int bq = 0; bq < K; bq++)
        acc = fmaf(wr[a * K + bq], tile[(y + a * DIL) * TW + (x + bq * DIL)], acc);
    dst[i] = acc;
  }
}

// ---- pointwise 16x16 conv; STATS0: per-channel (u) stats; STATS1: per-(b,c) stats ----
template<int STATS>
__global__ __launch_bounds__(256) void k_pw(const float* __restrict__ in, const float* __restrict__ w16,
                                            float* __restrict__ out, float* __restrict__ sacc,
                                            float* __restrict__ sqacc) {
  __shared__ float st[16][256];
  __shared__ float wsh[256];
  __shared__ float redS[16][4], redQ[16][4];
  int b = blockIdx.x >> 4, tile = blockIdx.x & 15;
  int t = threadIdx.x;
  wsh[t] = w16[t];
  size_t base = (size_t)b * 16 * HW + tile * 256;
  for (int i = 0; i < 16; i++) st[i][t] = in[base + (size_t)i * HW + t];
  __syncthreads();
  int w = t >> 6, lane = t & 63;
#pragma unroll
  for (int c = 0; c < 16; c++) {
    float acc = 0.f;
#pragma unroll
    for (int i = 0; i < 16; i++) acc = fmaf(wsh[c * 16 + i], st[i][t], acc);
    out[base + (size_t)c * HW + t] = acc;
    float s = wave_sum(acc), q = wave_sum(acc * acc);
    if (lane == 0) { redS[c][w] = s; redQ[c][w] = q; }
  }
  __syncthreads();
  if (t < 16) {
    float s = redS[t][0] + redS[t][1] + redS[t][2] + redS[t][3];
    float q = redQ[t][0] + redQ[t][1] + redQ[t][2] + redQ[t][3];
    if (STATS == 0) { atomicAdd(&sacc[t], s); atomicAdd(&sqacc[t], q); }
    else            { atomicAdd(&sacc[b * 16 + t], s); atomicAdd(&sqacc[b * 16 + t], q); }
  }
}

// ---- attention MLP + per-(b,k) accumulation coefficients ----
__global__ __launch_bounds__(128) void k_att(const float* __restrict__ S, const float* __restrict__ SQ,
                                             const float* __restrict__ w1, const float* __restrict__ w2,
                                             float* __restrict__ y, float* __restrict__ aco,
                                             float* __restrict__ bia) {
  int b = blockIdx.x, t = threadIdx.x;
  __shared__ float ym[128], h[16], msh[8][16], rssh[8][16], ysh[128];
  int op = t >> 4, k = t & 15;
  bool isbn = (op == 1 || op == 2 || op >= 4);
  float m = 0.f, rsc = 0.f;
  {
    float ss = 0.f, qq = 0.f;
    for (int bb = 0; bb < B; bb++) { ss += S[op * 512 + bb * 16 + k]; qq += SQ[op * 512 + bb * 16 + k]; }
    if (isbn) {
      m = ss * (1.f / (float)BHW);
      float var = qq * (1.f / (float)BHW) - m * m;
      rsc = rsqrtf(var + 1e-5f);
    }
  }
  msh[op][k] = m; rssh[op][k] = rsc;
  float sm = S[op * 512 + b * 16 + k] * (1.f / 4096.f);
  float yme = (op == 0) ? 0.f : ((op == 3) ? sm : (sm - m) * rsc);
  ym[t] = yme;
  __syncthreads();
  if (t < 16) {
    const float* wr = w1 + (size_t)t * 128;
    float acc = 0.f;
    for (int c = 0; c < 128; c++) acc = fmaf(wr[c], ym[c], acc);
    h[t] = fmaxf(acc, 0.f);
  }
  __syncthreads();
  {
    const float* wr = w2 + (size_t)t * 16;
    float acc = 0.f;
    for (int j = 0; j < 16; j++) acc = fmaf(wr[j], h[j], acc);
    float yy = 1.f / (1.f + expf(-acc));
    ysh[t] = yy; y[b * 128 + t] = yy;
  }
  __syncthreads();
  if (t < 16) {
    float bias = 0.f;
    for (int o2 = 1; o2 < 8; o2++) {
      float yv = ysh[o2 * 16 + t];
      float a;
      if (o2 == 3) a = yv;
      else { a = yv * rssh[o2][t]; bias -= yv * rssh[o2][t] * msh[o2][t]; }
      aco[(b * 16 + t) * 8 + o2] = a;
    }
    bia[b * 16 + t] = bias;
  }
}

// ---- op_attention: sum y over (b, c_sel) per op ----
__global__ __launch_bounds__(256) void k_opatt(const float* __restrict__ y, float* __restrict__ out8) {
  __shared__ float sh[256];
  int t = threadIdx.x, op = t >> 5, lane = t & 31;
  float acc = 0.f;
  for (int i = lane; i < 512; i += 32) { int b = i >> 4, k = i & 15; acc += y[b * 128 + op * 16 + k]; }
  sh[t] = acc;
  __syncthreads();
  if (lane == 0) {
    float s = 0.f;
    for (int i = 0; i < 32; i++) s += sh[op * 32 + i];
    out8[op] = s;
  }
}

// ---- final fused write ----
__global__ __launch_bounds__(256) void k_final(const float* __restrict__ x, const float* __restrict__ num,
                                               const int* __restrict__ selmap, const float* __restrict__ xt,
                                               const float* __restrict__ rbuf, const float* __restrict__ aco,
                                               const float* __restrict__ bia, float* __restrict__ out) {
  int bc = blockIdx.x, b = bc >> 8, c = bc & 255;
  int k = selmap[c];
  const float4* xs = (const float4*)(x + (size_t)bc * HW);
  float4* od = (float4*)(out + (size_t)bc * HW);
  if (k < 0) {
    float sc = 1.f + num[bc];
    for (int i = threadIdx.x; i < 1024; i += 256) {
      float4 v = xs[i];
      v.x *= sc; v.y *= sc; v.z *= sc; v.w *= sc;
      od[i] = v;
    }
  } else {
    int bk = b * 16 + k;
    const float4* xtp = (const float4*)(xt + (size_t)bk * HW);
    const float4* r0 = (const float4*)(rbuf + ((size_t)0 * 512 + bk) * HW);
    const float4* r1 = (const float4*)(rbuf + ((size_t)1 * 512 + bk) * HW);
    const float4* r2 = (const float4*)(rbuf + ((size_t)2 * 512 + bk) * HW);
    const float4* r3 = (const float4*)(rbuf + ((size_t)3 * 512 + bk) * HW);
    const float4* r4 = (const float4*)(rbuf + ((size_t)4 * 512 + bk) * HW);
    const float4* r5 = (const float4*)(rbuf + ((size_t)5 * 512 + bk) * HW);
    float a1 = aco[bk * 8 + 1], a2 = aco[bk * 8 + 2], a3 = aco[bk * 8 + 3], a4 = aco[bk * 8 + 4];
    float a5 = aco[bk * 8 + 5], a6 = aco[bk * 8 + 6], a7 = aco[bk * 8 + 7];
    float bias = bia[bk];
    for (int i = threadIdx.x; i < 1024; i += 256) {
      float4 xv = xs[i], tv = xtp[i];
      float4 v0 = r0[i], v1 = r1[i], v2 = r2[i], v3 = r3[i], v4 = r4[i], v5 = r5[i];
      float4 o;
      o.x = xv.x + bias + a1 * v0.x + a2 * v1.x + a3 * tv.x + a4 * v2.x + a5 * v3.x + a6 * v4.x + a7 * v5.x;
      o.y = xv.y + bias + a1 * v0.y + a2 * v1.y + a3 * tv.y + a4 * v2.y + a5 * v3.y + a6 * v4.y + a7 * v5.y;
      o.z = xv.z + bias + a1 * v0.z + a2 * v1.z + a3 * tv.z + a4 * v2.z + a5 * v3.z + a6 * v4.z + a7 * v5.z;
      o.w = xv.w + bias + a1 * v0.w + a2 * v1.w + a3 * tv.w + a4 * v2.w + a5 * v3.w + a6 * v4.w + a7 * v5.w;
      od[i] = o;
    }
  }
}

extern "C" void kernel_launch(void* const* d_in, const int* in_sizes, int n_in,
                              void* d_out, int out_size, void* d_ws, size_t ws_size,
                              hipStream_t stream) {
  const float* x      = (const float*)d_in[0];
  const float* ca_w1  = (const float*)d_in[1];
  const float* ca_w2  = (const float*)d_in[2];
  const float* s3_dw1 = (const float*)d_in[3];
  const float* s3_pw1 = (const float*)d_in[4];
  const float* s3_dw2 = (const float*)d_in[5];
  const float* s3_pw2 = (const float*)d_in[6];
  const float* s5_dw1 = (const float*)d_in[7];
  const float* s5_pw1 = (const float*)d_in[8];
  const float* s5_dw2 = (const float*)d_in[9];
  const float* s5_pw2 = (const float*)d_in[10];
  const float* d3_dw  = (const float*)d_in[11];
  const float* d3_pw  = (const float*)d_in[12];
  const float* d5_dw  = (const float*)d_in[13];
  const float* d5_pw  = (const float*)d_in[14];
  const float* at_w1  = (const float*)d_in[15];
  const float* at_w2  = (const float*)d_in[16];

  float* ws = (float*)d_ws;
  float* S = ws + OFF_S;  float* SQ = ws + OFF_SQ;  float* U = ws + OFF_U;
  float* mx = ws + OFF_MX; float* av = ws + OFF_AV; float* num = ws + OFF_NUM;
  float* slist = ws + OFF_SLIST;
  float* ybuf = ws + OFF_Y; float* aco = ws + OFF_ACO; float* bia = ws + OFF_BIAS;
  int* ib = (int*)(ws + OFF_INT);
  int* idx = ib; int* selmap = ib + 16;
  float* xt = ws + OFF_XT; float* R = ws + OFF_R;

  float* outf = (float*)d_out;
  float* t0 = outf;        // scratch inside d_out, dead before k_final
  float* t1 = outf + IMG;

  hipMemsetAsync(ws, 0, ACC_FLOATS * sizeof(float), stream);

  k_stats<<<B * C, 256, 0, stream>>>((const float4*)x, mx, av);
  k_se<<<B, 128, 0, stream>>>(mx, av, ca_w1, ca_w2, num);
  k_select<<<1, 256, 0, stream>>>(num, slist, idx, selmap);
  k_gather<<<B * CS, 256, 0, stream>>>(x, num, idx, xt, S + 3 * 512);

  k_pool<1><<<512, 256, 0, stream>>>(xt, R + 0 * IMG, S + 1 * 512, SQ + 1 * 512);
  k_pool<0><<<512, 256, 0, stream>>>(xt, R + 1 * IMG, S + 2 * 512, SQ + 2 * 512);

  // sep_conv 3x3 -> r slot 2 (op4)
  k_dw<3, 1, 0><<<512, 256, 0, stream>>>(xt, s3_dw1, t0, U);
  k_pw<0><<<512, 256, 0, stream>>>(t0, s3_pw1, t1, U + 0, U + 16);
  k_dw<3, 1, 1><<<512, 256, 0, stream>>>(t1, s3_dw2, t0, U + 0);
  k_pw<1><<<512, 256, 0, stream>>>(t0, s3_pw2, R + 2 * IMG, S + 4 * 512, SQ + 4 * 512);

  // sep_conv 5x5 -> r slot 3 (op5)
  k_dw<5, 1, 0><<<512, 256, 0, stream>>>(xt, s5_dw1, t0, U);
  k_pw<0><<<512, 256, 0, stream>>>(t0, s5_pw1, t1, U + 32, U + 48);
  k_dw<5, 1, 1><<<512, 256, 0, stream>>>(t1, s5_dw2, t0, U + 32);
  k_pw<1><<<512, 256, 0, stream>>>(t0, s5_pw2, R + 3 * IMG, S + 5 * 512, SQ + 5 * 512);

  // dil_conv 3x3 (dil=2) -> r slot 4 (op6)
  k_dw<3, 2, 0><<<512, 256, 0, stream>>>(xt, d3_dw, t0, U);
  k_pw<1><<<512, 256, 0, stream>>>(t0, d3_pw, R + 4 * IMG, S + 6 * 512, SQ + 6 * 512);

  // dil_conv 5x5 (dil=2) -> r slot 5 (op7)
  k_dw<5, 2, 0><<<512, 256, 0, stream>>>(xt, d5_dw, t0, U);
  k_pw<1><<<512, 256, 0, stream>>>(t0, d5_pw, R + 5 * IMG, S + 7 * 512, SQ + 7 * 512);

  k_att<<<B, 128, 0, stream>>>(S, SQ, at_w1, at_w2, ybuf, aco, bia);
  k_opatt<<<1, 256, 0, stream>>>(ybuf, outf + (size_t)B * C * HW);
  k_final<<<B * C, 256, 0, stream>>>(x, num, selmap, xt, R, aco, bia, outf);
}

// Round 2
// 311.862 us; speedup vs baseline: 1.2275x; 1.2275x over previous
//
#include <hip/hip_runtime.h>
#include <math.h>

static constexpr int B = 32, C = 256, HH = 64, WW = 64, HW = 4096, CS = 16;
static constexpr int BHW = B * HW;            // 131072
static constexpr size_t IMG = (size_t)B * CS * HW; // 2,097,152 floats per branch buffer

// ---------- workspace layout (floats) ----------
static constexpr size_t OFF_S     = 0;        // 8 ops x 512 (b*16+k) per-(b,c) sums
static constexpr size_t OFF_SQ    = 4096;     // 8 ops x 512 sumsq
static constexpr size_t OFF_U     = 8192;     // u1sum[16],u1sq[16],u2sum[16],u2sq[16]
static constexpr size_t ACC_FLOATS= 8256;     // zeroed each launch
static constexpr size_t OFF_MX    = 8256;
static constexpr size_t OFF_AV    = OFF_MX + 8192;
static constexpr size_t OFF_NUM   = OFF_AV + 8192;
static constexpr size_t OFF_SLIST = OFF_NUM + 8192;
static constexpr size_t OFF_Y     = OFF_SLIST + 256;   // B*128
static constexpr size_t OFF_ACO   = OFF_Y + 4096;      // B*16*8
static constexpr size_t OFF_BIAS  = OFF_ACO + 4096;    // B*16
static constexpr size_t OFF_INT   = OFF_BIAS + 512;    // idx[16], selmap[256] as ints
static constexpr size_t OFF_XT    = 42112;
static constexpr size_t OFF_R     = OFF_XT + IMG;      // 6 branch buffers

__device__ inline float wave_sum(float v) {
  v += __shfl_down(v, 32); v += __shfl_down(v, 16); v += __shfl_down(v, 8);
  v += __shfl_down(v, 4);  v += __shfl_down(v, 2);  v += __shfl_down(v, 1);
  return v;
}
__device__ inline float wave_max(float v) {
  v = fmaxf(v, __shfl_down(v, 32)); v = fmaxf(v, __shfl_down(v, 16));
  v = fmaxf(v, __shfl_down(v, 8));  v = fmaxf(v, __shfl_down(v, 4));
  v = fmaxf(v, __shfl_down(v, 2));  v = fmaxf(v, __shfl_down(v, 1));
  return v;
}

// ---- K1: per-(b,c) max and mean over HxW ----
__global__ __launch_bounds__(256) void k_stats(const float4* __restrict__ x,
                                               float* __restrict__ mx, float* __restrict__ av) {
  int bc = blockIdx.x;
  const float4* p = x + (size_t)bc * 1024;
  float mmax = -INFINITY, msum = 0.f;
  for (int i = threadIdx.x; i < 1024; i += 256) {
    float4 v = p[i];
    mmax = fmaxf(mmax, fmaxf(fmaxf(v.x, v.y), fmaxf(v.z, v.w)));
    msum += v.x + v.y + v.z + v.w;
  }
  __shared__ float rs[4], rm[4];
  float s = wave_sum(msum), m = wave_max(mmax);
  int w = threadIdx.x >> 6;
  if ((threadIdx.x & 63) == 0) { rs[w] = s; rm[w] = m; }
  __syncthreads();
  if (threadIdx.x == 0) {
    mx[bc] = fmaxf(fmaxf(rm[0], rm[1]), fmaxf(rm[2], rm[3]));
    av[bc] = (rs[0] + rs[1] + rs[2] + rs[3]) * (1.f / 4096.f);
  }
}

// ---- K2: SE module -> num = sigmoid(se(mx)+se(av)) ----
__global__ __launch_bounds__(128) void k_se(const float* __restrict__ mx, const float* __restrict__ av,
                                            const float* __restrict__ w1, const float* __restrict__ w2,
                                            float* __restrict__ num) {
  int b = blockIdx.x, t = threadIdx.x;
  __shared__ float zs[2][256], h[2][128];
  for (int i = t; i < 256; i += 128) { zs[0][i] = mx[b * 256 + i]; zs[1][i] = av[b * 256 + i]; }
  __syncthreads();
  {
    const float* wr = w1 + (size_t)t * 256;
    float am = 0.f, aa = 0.f;
    for (int i = 0; i < 256; i++) { float w = wr[i]; am = fmaf(w, zs[0][i], am); aa = fmaf(w, zs[1][i], aa); }
    h[0][t] = fmaxf(am, 0.f); h[1][t] = fmaxf(aa, 0.f);
  }
  __syncthreads();
  for (int c = t; c < 256; c += 128) {
    const float* wr = w2 + (size_t)c * 128;
    float sm = 0.f, sa = 0.f;
    for (int j = 0; j < 128; j++) { float w = wr[j]; sm = fmaf(w, h[0][j], sm); sa = fmaf(w, h[1][j], sa); }
    float s = sm + sa;
    num[b * 256 + c] = 1.f / (1.f + expf(-s));
  }
}

// ---- K3: slist + top-16, rank-based parallel (lax.top_k order: desc, ties->lowest idx) ----
__global__ __launch_bounds__(256) void k_select(const float* __restrict__ num, float* __restrict__ slist,
                                                int* __restrict__ idx, int* __restrict__ selmap) {
  __shared__ float s[256];
  int t = threadIdx.x;
  float acc = 0.f;
  for (int b = 0; b < B; b++) acc += num[b * 256 + t];
  s[t] = acc; slist[t] = acc; selmap[t] = -1;
  __syncthreads();
  float v = s[t];
  int rank = 0;
  for (int c = 0; c < 256; c++) {
    float o = s[c];
    rank += (o > v) || (o == v && c < t);
  }
  if (rank < 16) { idx[rank] = t; selmap[t] = rank; }
}

// ---- K4: xt = x[:,idx]*num ; also per-(b,k) sum (identity-branch mean) ----
__global__ __launch_bounds__(256) void k_gather(const float* __restrict__ x, const float* __restrict__ num,
                                                const int* __restrict__ idx, float* __restrict__ xt,
                                                float* __restrict__ Sdst) {
  int bk = blockIdx.x, b = bk >> 4, k = bk & 15;
  int c = idx[k];
  float sc = num[b * 256 + c];
  const float4* src = (const float4*)(x + ((size_t)b * 256 + c) * HW);
  float4* dst = (float4*)(xt + (size_t)bk * HW);
  float sum = 0.f;
  for (int i = threadIdx.x; i < 1024; i += 256) {
    float4 v = src[i];
    v.x *= sc; v.y *= sc; v.z *= sc; v.w *= sc;
    dst[i] = v; sum += v.x + v.y + v.z + v.w;
  }
  __shared__ float rs[4];
  float s = wave_sum(sum);
  if ((threadIdx.x & 63) == 0) rs[threadIdx.x >> 6] = s;
  __syncthreads();
  if (threadIdx.x == 0) Sdst[bk] = rs[0] + rs[1] + rs[2] + rs[3];
}

// ---- pools (3x3 stride1 pad1), write raw output + per-(b,c) sum/sumsq ----
template<int ISMAX>
__global__ __launch_bounds__(256) void k_pool(const float* __restrict__ xt, float* __restrict__ r,
                                              float* __restrict__ Sdst, float* __restrict__ SQdst) {
  __shared__ float tile[64 * 64];
  int bk = blockIdx.x;
  const float* src = xt + (size_t)bk * HW;
  for (int i = threadIdx.x; i < HW; i += 256) tile[i] = src[i];
  __syncthreads();
  float sum = 0.f, sq = 0.f;
  for (int i = threadIdx.x; i < HW; i += 256) {
    int y = i >> 6, x = i & 63;
    int y0 = max(y - 1, 0), y1 = min(y + 1, 63), x0 = max(x - 1, 0), x1 = min(x + 1, 63);
    float o;
    if (ISMAX) {
      o = -INFINITY;
      for (int yy = y0; yy <= y1; yy++)
        for (int xx = x0; xx <= x1; xx++) o = fmaxf(o, tile[yy * 64 + xx]);
    } else {
      float a = 0.f;
      for (int yy = y0; yy <= y1; yy++)
        for (int xx = x0; xx <= x1; xx++) a += tile[yy * 64 + xx];
      o = a / (float)((y1 - y0 + 1) * (x1 - x0 + 1));
    }
    r[(size_t)bk * HW + i] = o; sum += o; sq += o * o;
  }
  __shared__ float rs[4], rq[4];
  float s = wave_sum(sum), q = wave_sum(sq);
  if ((threadIdx.x & 63) == 0) { rs[threadIdx.x >> 6] = s; rq[threadIdx.x >> 6] = q; }
  __syncthreads();
  if (threadIdx.x == 0) {
    Sdst[bk] = rs[0] + rs[1] + rs[2] + rs[3];
    SQdst[bk] = rq[0] + rq[1] + rq[2] + rq[3];
  }
}

// ---- depthwise conv, MODE0: relu(in); MODE1: relu((in-m)*rs) with channel stats from ustats ----
template<int K, int DIL, int MODE>
__global__ __launch_bounds__(256) void k_dw(const float* __restrict__ in, const float* __restrict__ w,
                                            float* __restrict__ out, const float* __restrict__ ustats) {
  constexpr int P = (K / 2) * DIL;
  constexpr int TW = 64 + 2 * P;
  __shared__ float tile[TW * TW];
  __shared__ float sm_, srs_;
  int bk = blockIdx.x, k = bk & 15;
  if (MODE == 1) {
    if (threadIdx.x == 0) {
      float mu = ustats[k] * (1.f / (float)BHW);
      float var = ustats[16 + k] * (1.f / (float)BHW) - mu * mu;
      sm_ = mu; srs_ = rsqrtf(var + 1e-5f);
    }
    __syncthreads();
  }
  float m = (MODE == 1) ? sm_ : 0.f, rsc = (MODE == 1) ? srs_ : 1.f;
  float wr[K * K];
#pragma unroll
  for (int i = 0; i < K * K; i++) wr[i] = w[k * K * K + i];
  const float* src = in + (size_t)bk * HW;
  for (int i = threadIdx.x; i < TW * TW; i += 256) {
    int ty = i / TW, tx = i - ty * TW;
    int y = ty - P, x = tx - P;
    float v = 0.f;
    if (y >= 0 && y < 64 && x >= 0 && x < 64) {
      v = src[y * 64 + x];
      if (MODE == 1) v = (v - m) * rsc;
      v = fmaxf(v, 0.f);
    }
    tile[i] = v;
  }
  __syncthreads();
  float* dst = out + (size_t)bk * HW;
  for (int i = threadIdx.x; i < HW; i += 256) {
    int y = i >> 6, x = i & 63;
    float acc = 0.f;
#pragma unroll
    for (int a = 0; a < K; a++)
#pragma unroll
      for (int bq = 0; bq < K; bq++)
        acc = fmaf(wr[a * K + bq], tile[(y + a * DIL) * TW + (x + bq * DIL)], acc);
    dst[i] = acc;
  }
}

// ---- pointwise 16x16 conv; STATS0: per-channel (u) stats; STATS1: per-(b,c) stats ----
template<int STATS>
__global__ __launch_bounds__(256) void k_pw(const float* __restrict__ in, const float* __restrict__ w16,
                                            float* __restrict__ out, float* __restrict__ sacc,
                                            float* __restrict__ sqacc) {
  __shared__ float st[16][256];
  __shared__ float wsh[256];
  __shared__ float redS[16][4], redQ[16][4];
  int b = blockIdx.x >> 4, tile = blockIdx.x & 15;
  int t = threadIdx.x;
  wsh[t] = w16[t];
  size_t base = (size_t)b * 16 * HW + tile * 256;
  for (int i = 0; i < 16; i++) st[i][t] = in[base + (size_t)i * HW + t];
  __syncthreads();
  int w = t >> 6, lane = t & 63;
#pragma unroll
  for (int c = 0; c < 16; c++) {
    float acc = 0.f;
#pragma unroll
    for (int i = 0; i < 16; i++) acc = fmaf(wsh[c * 16 + i], st[i][t], acc);
    out[base + (size_t)c * HW + t] = acc;
    float s = wave_sum(acc), q = wave_sum(acc * acc);
    if (lane == 0) { redS[c][w] = s; redQ[c][w] = q; }
  }
  __syncthreads();
  if (t < 16) {
    float s = redS[t][0] + redS[t][1] + redS[t][2] + redS[t][3];
    float q = redQ[t][0] + redQ[t][1] + redQ[t][2] + redQ[t][3];
    if (STATS == 0) { atomicAdd(&sacc[t], s); atomicAdd(&sqacc[t], q); }
    else            { atomicAdd(&sacc[b * 16 + t], s); atomicAdd(&sqacc[b * 16 + t], q); }
  }
}

// ---- attention MLP + per-(b,k) accumulation coefficients ----
__global__ __launch_bounds__(128) void k_att(const float* __restrict__ S, const float* __restrict__ SQ,
                                             const float* __restrict__ w1, const float* __restrict__ w2,
                                             float* __restrict__ y, float* __restrict__ aco,
                                             float* __restrict__ bia) {
  int b = blockIdx.x, t = threadIdx.x;
  __shared__ float ym[128], h[16], msh[8][16], rssh[8][16], ysh[128];
  int op = t >> 4, k = t & 15;
  bool isbn = (op == 1 || op == 2 || op >= 4);
  float m = 0.f, rsc = 0.f;
  {
    float ss = 0.f, qq = 0.f;
    for (int bb = 0; bb < B; bb++) { ss += S[op * 512 + bb * 16 + k]; qq += SQ[op * 512 + bb * 16 + k]; }
    if (isbn) {
      m = ss * (1.f / (float)BHW);
      float var = qq * (1.f / (float)BHW) - m * m;
      rsc = rsqrtf(var + 1e-5f);
    }
  }
  msh[op][k] = m; rssh[op][k] = rsc;
  float sm = S[op * 512 + b * 16 + k] * (1.f / 4096.f);
  float yme = (op == 0) ? 0.f : ((op == 3) ? sm : (sm - m) * rsc);
  ym[t] = yme;
  __syncthreads();
  if (t < 16) {
    const float* wr = w1 + (size_t)t * 128;
    float acc = 0.f;
    for (int c = 0; c < 128; c++) acc = fmaf(wr[c], ym[c], acc);
    h[t] = fmaxf(acc, 0.f);
  }
  __syncthreads();
  {
    const float* wr = w2 + (size_t)t * 16;
    float acc = 0.f;
    for (int j = 0; j < 16; j++) acc = fmaf(wr[j], h[j], acc);
    float yy = 1.f / (1.f + expf(-acc));
    ysh[t] = yy; y[b * 128 + t] = yy;
  }
  __syncthreads();
  if (t < 16) {
    float bias = 0.f;
    for (int o2 = 1; o2 < 8; o2++) {
      float yv = ysh[o2 * 16 + t];
      float a;
      if (o2 == 3) a = yv;
      else { a = yv * rssh[o2][t]; bias -= yv * rssh[o2][t] * msh[o2][t]; }
      aco[(b * 16 + t) * 8 + o2] = a;
    }
    bia[b * 16 + t] = bias;
  }
}

// ---- op_attention: sum y over (b, c_sel) per op ----
__global__ __launch_bounds__(256) void k_opatt(const float* __restrict__ y, float* __restrict__ out8) {
  __shared__ float sh[256];
  int t = threadIdx.x, op = t >> 5, lane = t & 31;
  float acc = 0.f;
  for (int i = lane; i < 512; i += 32) { int b = i >> 4, k = i & 15; acc += y[b * 128 + op * 16 + k]; }
  sh[t] = acc;
  __syncthreads();
  if (lane == 0) {
    float s = 0.f;
    for (int i = 0; i < 32; i++) s += sh[op * 32 + i];
    out8[op] = s;
  }
}

// ---- final fused write ----
__global__ __launch_bounds__(256) void k_final(const float* __restrict__ x, const float* __restrict__ num,
                                               const int* __restrict__ selmap, const float* __restrict__ xt,
                                               const float* __restrict__ rbuf, const float* __restrict__ aco,
                                               const float* __restrict__ bia, float* __restrict__ out) {
  int bc = blockIdx.x, b = bc >> 8, c = bc & 255;
  int k = selmap[c];
  const float4* xs = (const float4*)(x + (size_t)bc * HW);
  float4* od = (float4*)(out + (size_t)bc * HW);
  if (k < 0) {
    float sc = 1.f + num[bc];
    for (int i = threadIdx.x; i < 1024; i += 256) {
      float4 v = xs[i];
      v.x *= sc; v.y *= sc; v.z *= sc; v.w *= sc;
      od[i] = v;
    }
  } else {
    int bk = b * 16 + k;
    const float4* xtp = (const float4*)(xt + (size_t)bk * HW);
    const float4* r0 = (const float4*)(rbuf + ((size_t)0 * 512 + bk) * HW);
    const float4* r1 = (const float4*)(rbuf + ((size_t)1 * 512 + bk) * HW);
    const float4* r2 = (const float4*)(rbuf + ((size_t)2 * 512 + bk) * HW);
    const float4* r3 = (const float4*)(rbuf + ((size_t)3 * 512 + bk) * HW);
    const float4* r4 = (const float4*)(rbuf + ((size_t)4 * 512 + bk) * HW);
    const float4* r5 = (const float4*)(rbuf + ((size_t)5 * 512 + bk) * HW);
    float a1 = aco[bk * 8 + 1], a2 = aco[bk * 8 + 2], a3 = aco[bk * 8 + 3], a4 = aco[bk * 8 + 4];
    float a5 = aco[bk * 8 + 5], a6 = aco[bk * 8 + 6], a7 = aco[bk * 8 + 7];
    float bias = bia[bk];
    for (int i = threadIdx.x; i < 1024; i += 256) {
      float4 xv = xs[i], tv = xtp[i];
      float4 v0 = r0[i], v1 = r1[i], v2 = r2[i], v3 = r3[i], v4 = r4[i], v5 = r5[i];
      float4 o;
      o.x = xv.x + bias + a1 * v0.x + a2 * v1.x + a3 * tv.x + a4 * v2.x + a5 * v3.x + a6 * v4.x + a7 * v5.x;
      o.y = xv.y + bias + a1 * v0.y + a2 * v1.y + a3 * tv.y + a4 * v2.y + a5 * v3.y + a6 * v4.y + a7 * v5.y;
      o.z = xv.z + bias + a1 * v0.z + a2 * v1.z + a3 * tv.z + a4 * v2.z + a5 * v3.z + a6 * v4.z + a7 * v5.z;
      o.w = xv.w + bias + a1 * v0.w + a2 * v1.w + a3 * tv.w + a4 * v2.w + a5 * v3.w + a6 * v4.w + a7 * v5.w;
      od[i] = o;
    }
  }
}

extern "C" void kernel_launch(void* const* d_in, const int* in_sizes, int n_in,
                              void* d_out, int out_size, void* d_ws, size_t ws_size,
                              hipStream_t stream) {
  const float* x      = (const float*)d_in[0];
  const float* ca_w1  = (const float*)d_in[1];
  const float* ca_w2  = (const float*)d_in[2];
  const float* s3_dw1 = (const float*)d_in[3];
  const float* s3_pw1 = (const float*)d_in[4];
  const float* s3_dw2 = (const float*)d_in[5];
  const float* s3_pw2 = (const float*)d_in[6];
  const float* s5_dw1 = (const float*)d_in[7];
  const float* s5_pw1 = (const float*)d_in[8];
  const float* s5_dw2 = (const float*)d_in[9];
  const float* s5_pw2 = (const float*)d_in[10];
  const float* d3_dw  = (const float*)d_in[11];
  const float* d3_pw  = (const float*)d_in[12];
  const float* d5_dw  = (const float*)d_in[13];
  const float* d5_pw  = (const float*)d_in[14];
  const float* at_w1  = (const float*)d_in[15];
  const float* at_w2  = (const float*)d_in[16];

  float* ws = (float*)d_ws;
  float* S = ws + OFF_S;  float* SQ = ws + OFF_SQ;  float* U = ws + OFF_U;
  float* mx = ws + OFF_MX; float* av = ws + OFF_AV; float* num = ws + OFF_NUM;
  float* slist = ws + OFF_SLIST;
  float* ybuf = ws + OFF_Y; float* aco = ws + OFF_ACO; float* bia = ws + OFF_BIAS;
  int* ib = (int*)(ws + OFF_INT);
  int* idx = ib; int* selmap = ib + 16;
  float* xt = ws + OFF_XT; float* R = ws + OFF_R;

  float* outf = (float*)d_out;
  float* t0 = outf;        // scratch inside d_out, dead before k_final
  float* t1 = outf + IMG;

  hipMemsetAsync(ws, 0, ACC_FLOATS * sizeof(float), stream);

  k_stats<<<B * C, 256, 0, stream>>>((const float4*)x, mx, av);
  k_se<<<B, 128, 0, stream>>>(mx, av, ca_w1, ca_w2, num);
  k_select<<<1, 256, 0, stream>>>(num, slist, idx, selmap);
  k_gather<<<B * CS, 256, 0, stream>>>(x, num, idx, xt, S + 3 * 512);

  k_pool<1><<<512, 256, 0, stream>>>(xt, R + 0 * IMG, S + 1 * 512, SQ + 1 * 512);
  k_pool<0><<<512, 256, 0, stream>>>(xt, R + 1 * IMG, S + 2 * 512, SQ + 2 * 512);

  // sep_conv 3x3 -> r slot 2 (op4)
  k_dw<3, 1, 0><<<512, 256, 0, stream>>>(xt, s3_dw1, t0, U);
  k_pw<0><<<512, 256, 0, stream>>>(t0, s3_pw1, t1, U + 0, U + 16);
  k_dw<3, 1, 1><<<512, 256, 0, stream>>>(t1, s3_dw2, t0, U + 0);
  k_pw<1><<<512, 256, 0, stream>>>(t0, s3_pw2, R + 2 * IMG, S + 4 * 512, SQ + 4 * 512);

  // sep_conv 5x5 -> r slot 3 (op5)
  k_dw<5, 1, 0><<<512, 256, 0, stream>>>(xt, s5_dw1, t0, U);
  k_pw<0><<<512, 256, 0, stream>>>(t0, s5_pw1, t1, U + 32, U + 48);
  k_dw<5, 1, 1><<<512, 256, 0, stream>>>(t1, s5_dw2, t0, U + 32);
  k_pw<1><<<512, 256, 0, stream>>>(t0, s5_pw2, R + 3 * IMG, S + 5 * 512, SQ + 5 * 512);

  // dil_conv 3x3 (dil=2) -> r slot 4 (op6)
  k_dw<3, 2, 0><<<512, 256, 0, stream>>>(xt, d3_dw, t0, U);
  k_pw<1><<<512, 256, 0, stream>>>(t0, d3_pw, R + 4 * IMG, S + 6 * 512, SQ + 6 * 512);

  // dil_conv 5x5 (dil=2) -> r slot 5 (op7)
  k_dw<5, 2, 0><<<512, 256, 0, stream>>>(xt, d5_dw, t0, U);
  k_pw<1><<<512, 256, 0, stream>>>(t0, d5_pw, R + 5 * IMG, S + 7 * 512, SQ + 7 * 512);

  k_att<<<B, 128, 0, stream>>>(S, SQ, at_w1, at_w2, ybuf, aco, bia);
  k_opatt<<<1, 256, 0, stream>>>(ybuf, outf + (size_t)B * C * HW);
  k_final<<<B * C, 256, 0, stream>>>(x, num, selmap, xt, R, aco, bia, outf);
}